// Round 3
// baseline (1466.518 us; speedup 1.0000x reference)
//
#include <hip/hip_runtime.h>
#include <hip/hip_fp16.h>

// RNN h_{t+1} = tanh(x_t*W_ih + b_ih + b_hh + h_t @ W_hh^T), T=1024, B=64, H=512.
//
// Round 3: ONE WG (512 thr, 8 waves) per batch, one CU per chain. No cross-WG
// traffic at all: h passes step-to-step through LDS + one __syncthreads.
//  - Thread owns rows jA=64w+2i, jB=jA+1 over k-half c=lane>>5 (256 k each).
//    512 fp16 weights/thread: 384 in VGPRs (192 regs), 128 in LDS (128KB total).
//  - LDS weight tail uses XOR chunk swizzle ((ch ^ tid)&7) -> conflict-free
//    ds_read_b128 (linear layout would be 32-way conflicted).
//  - h stored as half2 in LDS, parity double-buffered; reads are 2-way
//    broadcast (lanes of same k-half read the same address) = free.
//  - k-half partials combined with one shfl_xor(32); lanes c==0 publish.
// Step model: 1024cy VALU (256 v_dot2_f32_f16/thread) + ~500cy LDS overlapped.

#define BB 64
#define TT 1024
#define HH 512
#define REG_CH 24   // 16B h-chunks whose weights sit in VGPRs (k-rel [0,192))
#define LDS_CH 8    // 16B h-chunks whose weights sit in LDS   (k-rel [192,256))

typedef _Float16 half2_t __attribute__((ext_vector_type(2)));

__device__ __forceinline__ float dot2f(unsigned h, unsigned w, float acc) {
#if __has_builtin(__builtin_amdgcn_fdot2)
    return __builtin_amdgcn_fdot2(__builtin_bit_cast(half2_t, h),
                                  __builtin_bit_cast(half2_t, w), acc, false);
#else
    __half2 hh = __builtin_bit_cast(__half2, h);
    __half2 ww = __builtin_bit_cast(__half2, w);
    acc = fmaf(__low2float(hh), __low2float(ww), acc);
    return fmaf(__high2float(hh), __high2float(ww), acc);
#endif
}

__device__ __forceinline__ float fast_tanh(float z) {
    float e = __expf(2.0f * z);
    return fmaf(-2.0f, __builtin_amdgcn_rcpf(e + 1.0f), 1.0f);
}

__device__ __forceinline__ unsigned pack_h2(float a, float b) {
    return __builtin_bit_cast(unsigned, __floats2half2_rn(a, b));
}

__launch_bounds__(512, 2)
__global__ void rnn_batch_cu(const float* __restrict__ x,      // [B,T]
                             const float* __restrict__ W_ih,   // [H]
                             const float* __restrict__ W_hh,   // [H,H]
                             const float* __restrict__ b_ih,   // [H]
                             const float* __restrict__ b_hh,   // [H]
                             const float* __restrict__ W_out,  // [H]
                             const float* __restrict__ b_out,  // [1]
                             float* __restrict__ out)          // [64 + B*H]
{
    const int b    = blockIdx.x;
    const int tid  = threadIdx.x;
    const int w    = tid >> 6;          // wave 0..7
    const int lane = tid & 63;
    const int i    = lane & 31;
    const int c    = lane >> 5;         // k-half

    __shared__ unsigned h2[2][HH / 2];                  // 2KB  [parity][256]
    __shared__ float xrow[TT];                          // 4KB
    __shared__ __align__(16) unsigned wtail[512 * 64];  // 128KB weight tails

    const int jA    = 64 * w + 2 * i;
    const int jB    = jA + 1;
    const int kbase = c * 256;

    // ---- stage x row ----
    for (int s = tid; s < TT; s += 512) xrow[s] = x[b * TT + s];

    // ---- weights: regs (k-rel [0,192)) + LDS tail (k-rel [192,256)) ----
    unsigned wrA[96], wrB[96];
    {
        const float2* rA = reinterpret_cast<const float2*>(W_hh + (size_t)jA * HH + kbase);
        const float2* rB = reinterpret_cast<const float2*>(W_hh + (size_t)jB * HH + kbase);
#pragma unroll
        for (int d = 0; d < 96; ++d) {
            float2 a = rA[d], e = rB[d];
            wrA[d] = pack_h2(a.x, a.y);
            wrB[d] = pack_h2(e.x, e.y);
        }
        // tails: 16 logical 16B chunks (0..7 row A, 8..15 row B), XOR-swizzled
        uint4* tb = reinterpret_cast<uint4*>(&wtail[tid * 64]);
#pragma unroll
        for (int l = 0; l < 16; ++l) {
            const float2* rr = (l < 8) ? rA : rB;
            const int d0 = 96 + 4 * (l & 7);
            float2 p0 = rr[d0], p1 = rr[d0 + 1], p2 = rr[d0 + 2], p3 = rr[d0 + 3];
            uint4 u;
            u.x = pack_h2(p0.x, p0.y);
            u.y = pack_h2(p1.x, p1.y);
            u.z = pack_h2(p2.x, p2.y);
            u.w = pack_h2(p3.x, p3.y);
            tb[(l & 8) | ((l ^ tid) & 7)] = u;
        }
    }

    // per-thread bias/input-weight constants (same for both k-halves of a row)
    const float wihA = W_ih[jA], wihB = W_ih[jB];
    const float bA = b_ih[jA] + b_hh[jA];
    const float bB = b_ih[jB] + b_hh[jB];

    __syncthreads();   // xrow + wtail visible

#pragma unroll 1
    for (int t = 0; t < TT; ++t) {
        float aA0 = 0.f, aA1 = 0.f, aB0 = 0.f, aB1 = 0.f;
        if (t > 0) {
            const uint4* hp = reinterpret_cast<const uint4*>(&h2[t & 1][c * 128]);
            const uint4* tb = reinterpret_cast<const uint4*>(&wtail[tid * 64]);
#pragma unroll
            for (int ch = 0; ch < REG_CH; ++ch) {
                const uint4 u = hp[ch];
                aA0 = dot2f(u.x, wrA[4*ch+0], aA0); aB0 = dot2f(u.x, wrB[4*ch+0], aB0);
                aA1 = dot2f(u.y, wrA[4*ch+1], aA1); aB1 = dot2f(u.y, wrB[4*ch+1], aB1);
                aA0 = dot2f(u.z, wrA[4*ch+2], aA0); aB0 = dot2f(u.z, wrB[4*ch+2], aB0);
                aA1 = dot2f(u.w, wrA[4*ch+3], aA1); aB1 = dot2f(u.w, wrB[4*ch+3], aB1);
            }
#pragma unroll
            for (int ch = 0; ch < LDS_CH; ++ch) {
                const uint4 u  = hp[REG_CH + ch];
                const uint4 wa = tb[(ch ^ tid) & 7];
                const uint4 wb = tb[8 | ((ch ^ tid) & 7)];
                aA0 = dot2f(u.x, wa.x, aA0); aB0 = dot2f(u.x, wb.x, aB0);
                aA1 = dot2f(u.y, wa.y, aA1); aB1 = dot2f(u.y, wb.y, aB1);
                aA0 = dot2f(u.z, wa.z, aA0); aB0 = dot2f(u.z, wb.z, aB0);
                aA1 = dot2f(u.w, wa.w, aA1); aB1 = dot2f(u.w, wb.w, aB1);
            }
        }
        float zA = aA0 + aA1;
        float zB = aB0 + aB1;
        zA += __shfl_xor(zA, 32, 64);   // combine the two k-halves
        zB += __shfl_xor(zB, 32, 64);
        const float xt = xrow[t];
        zA = fmaf(xt, wihA, zA + bA);
        zB = fmaf(xt, wihB, zB + bB);
        const float hA = fast_tanh(zA);
        const float hB = fast_tanh(zB);
        if (c == 0) {
            h2[(t + 1) & 1][32 * w + i] = pack_h2(hA, hB);
            if (t == TT - 1) {
                out[64 + b * HH + jA] = hA;
                out[64 + b * HH + jB] = hB;
            }
        }
        __syncthreads();   // the ONLY barrier per step
    }

    // ---- epilogue: wave 0 computes out[b] = h_last . W_out + b_out ----
    if (w == 0) {
        const uint4 hv = reinterpret_cast<const uint4*>(&h2[TT & 1][0])[lane];
        const float4 w0 = reinterpret_cast<const float4*>(W_out)[2 * lane + 0];
        const float4 w1 = reinterpret_cast<const float4*>(W_out)[2 * lane + 1];
        float s = 0.f;
        __half2 p;
        p = __builtin_bit_cast(__half2, hv.x);
        s = fmaf(__low2float(p), w0.x, s); s = fmaf(__high2float(p), w0.y, s);
        p = __builtin_bit_cast(__half2, hv.y);
        s = fmaf(__low2float(p), w0.z, s); s = fmaf(__high2float(p), w0.w, s);
        p = __builtin_bit_cast(__half2, hv.z);
        s = fmaf(__low2float(p), w1.x, s); s = fmaf(__high2float(p), w1.y, s);
        p = __builtin_bit_cast(__half2, hv.w);
        s = fmaf(__low2float(p), w1.z, s); s = fmaf(__high2float(p), w1.w, s);
#pragma unroll
        for (int off = 32; off; off >>= 1) s += __shfl_down(s, off, 64);
        if (lane == 0) out[b] = s + b_out[0];
    }
}

extern "C" void kernel_launch(void* const* d_in, const int* in_sizes, int n_in,
                              void* d_out, int out_size, void* d_ws, size_t ws_size,
                              hipStream_t stream) {
    const float* x     = (const float*)d_in[0];  // inputs [B,T,1]
    // d_in[1] = state (ignored; reference uses zero initial hidden state)
    const float* W_ih  = (const float*)d_in[2];
    const float* W_hh  = (const float*)d_in[3];
    const float* b_ih  = (const float*)d_in[4];
    const float* b_hh  = (const float*)d_in[5];
    const float* W_out = (const float*)d_in[6];
    const float* b_out = (const float*)d_in[7];

    rnn_batch_cu<<<dim3(BB), dim3(512), 0, stream>>>(
        x, W_ih, W_hh, b_ih, b_hh, W_out, b_out, (float*)d_out);
}

// Round 4
// 1425.683 us; speedup vs baseline: 1.0286x; 1.0286x over previous
//
#include <hip/hip_runtime.h>
#include <hip/hip_fp16.h>

// RNN h_{t+1} = tanh(x_t*W_ih + b_ih + b_hh + h_t @ W_hh^T), T=1024, B=64, H=512.
//
// Round 4: 64 teams x 4 WGs, each team SELF-ORGANIZED onto ONE XCD (runtime
// XCC_ID discovery + agent-scope bulletin), so the per-step h exchange is
// XCD-L2-local (~200cy) instead of L3/fabric (~700+cy, round-2 bottleneck).
//  - WG role q owns j-slice [q*128,(q+1)*128); weights fp16 register-resident
//    (128 VGPR/thread). Wave w handles k-slice w.
//  - Exchange word = {tag:32|half2:32}, 8B aligned: publisher -> plain
//    global_store_dwordx2 (write-through to local L2, stays dirty); poller ->
//    global_atomic_add_x2 +0 sc0 (executes AT the L2, never L1, no sc1 -> local).
//  - Wave q never polls (its slice is local via LDS); waves w!=q poll slice w
//    and overlap their poll with the publisher's reduce/tanh.
//  - ONE __syncthreads per step; parity double-buffering makes it race-free
//    (skew bound <=1 step, same proof as round 2).

#define BB 64
#define TT 1024
#define HH 512

typedef _Float16 half2_t __attribute__((ext_vector_type(2)));

__device__ __forceinline__ float dot2f(unsigned h, unsigned w, float acc) {
#if __has_builtin(__builtin_amdgcn_fdot2)
    return __builtin_amdgcn_fdot2(__builtin_bit_cast(half2_t, h),
                                  __builtin_bit_cast(half2_t, w), acc, false);
#else
    __half2 hh = __builtin_bit_cast(__half2, h);
    __half2 ww = __builtin_bit_cast(__half2, w);
    acc = fmaf(__low2float(hh), __low2float(ww), acc);
    return fmaf(__high2float(hh), __high2float(ww), acc);
#endif
}

__device__ __forceinline__ float fast_tanh(float z) {
    float e = __expf(2.0f * z);
    return fmaf(-2.0f, __builtin_amdgcn_rcpf(e + 1.0f), 1.0f);
}

__device__ __forceinline__ unsigned pack_h2(float a, float b) {
    return __builtin_bit_cast(unsigned, __floats2half2_rn(a, b));
}

// 8B read that executes at the local XCD L2 (atomics bypass L1; sc0=return old;
// no sc1 keeps it XCD-local). Adds 0 -> value unchanged.
__device__ __forceinline__ unsigned long long l2_read_u64(unsigned long long* p) {
    unsigned long long old;
    unsigned long long zero = 0;
    asm volatile("global_atomic_add_x2 %0, %1, %2, off sc0\n\t"
                 "s_waitcnt vmcnt(0)"
                 : "=v"(old) : "v"(p), "v"(zero) : "memory");
    return old;
}

// plain 8B store: write-through L1, lands in local XCD L2 (single-copy atomic)
__device__ __forceinline__ void l2_write_u64(unsigned long long* p, unsigned long long v) {
    asm volatile("global_store_dwordx2 %0, %1, off" :: "v"(p), "v"(v) : "memory");
}

#define AG __HIP_MEMORY_SCOPE_AGENT

__launch_bounds__(256, 2)
__global__ void rnn_xcd(const float* __restrict__ x,      // [B,T]
                        const float* __restrict__ W_ih,   // [H]
                        const float* __restrict__ W_hh,   // [H,H]
                        const float* __restrict__ b_ih,   // [H]
                        const float* __restrict__ b_hh,   // [H]
                        const float* __restrict__ W_out,  // [H]
                        const float* __restrict__ b_out,  // [1]
                        float* __restrict__ out,          // [64 + B*H]
                        unsigned* __restrict__ ctl,       // bulletin (8KB)
                        unsigned long long* __restrict__ hg) // [2][B][4][64]
{
    const int tid  = threadIdx.x;
    const int w    = tid >> 6;          // wave id = k-slice 0..3
    const int lane = tid & 63;

    __shared__ float parts[2][4][128];          // [parity][k-wave][local j]
    __shared__ float xrow[TT];
    __shared__ __align__(16) unsigned h2w[4][64];    // polled remote slices
    __shared__ __align__(16) unsigned h2local[2][64];// own slice, [parity]
    __shared__ unsigned shr;

    // ================= team formation (XCD-local quads) =================
    // ctl[0]=next_batch, ctl[1]=formed, ctl[2..9]=cnt[xcd], ctl[16..]=team_batch[8][128]
    if (tid == 0) {
        unsigned xcd;
        asm volatile("s_getreg_b32 %0, hwreg(HW_REG_XCC_ID)" : "=s"(xcd));
        xcd &= 7;
        unsigned slot = __hip_atomic_fetch_add(&ctl[2 + xcd], 1u, __ATOMIC_RELAXED, AG);
        unsigned team = slot >> 2, role = slot & 3;
        unsigned* tb = &ctl[16 + xcd * 128 + team];
        unsigned enc;
        if (role == 3) {
            unsigned bt = __hip_atomic_fetch_add(&ctl[0], 1u, __ATOMIC_RELAXED, AG);
            enc = (bt < BB) ? (0x100u | bt) : 0x1FFu;
            __hip_atomic_store(tb, enc, __ATOMIC_RELEASE, AG);
            if (bt < BB) __hip_atomic_fetch_add(&ctl[1], 1u, __ATOMIC_RELEASE, AG);
        } else {
            for (;;) {
                enc = __hip_atomic_load(tb, __ATOMIC_ACQUIRE, AG);
                if (enc) break;
                if (__hip_atomic_load(&ctl[1], __ATOMIC_ACQUIRE, AG) >= BB) {
                    // all 64 valid teams formed & visible; if ours isn't, it never will be
                    enc = __hip_atomic_load(tb, __ATOMIC_ACQUIRE, AG);
                    if (!enc) enc = 0x1FFu;
                    break;
                }
                __builtin_amdgcn_s_sleep(8);
            }
        }
        shr = enc | (role << 16);
    }
    __syncthreads();
    const unsigned er = shr;
    if ((er & 0xFFu) == 0xFFu) return;   // surplus quad: exit before any loading
    const int b = er & 0xFFu;
    const int q = (er >> 16) & 3;

    // ================= prologue: weights, x row, constants =================
    const int j0 = q * 128 + lane;      // dot-side rows of this thread
    const int j1 = j0 + 64;
    const int k0 = w * 128;
    unsigned wh0[64], wh1[64];
    {
        const float2* r0 = reinterpret_cast<const float2*>(W_hh + (size_t)j0 * HH + k0);
        const float2* r1 = reinterpret_cast<const float2*>(W_hh + (size_t)j1 * HH + k0);
#pragma unroll
        for (int d = 0; d < 64; ++d) {
            float2 a = r0[d], c = r1[d];
            wh0[d] = pack_h2(a.x, a.y);
            wh1[d] = pack_h2(c.x, c.y);
        }
    }
    for (int s = tid; s < TT; s += 256) xrow[s] = x[b * TT + s];

    // publisher constants (wave q, all 64 lanes; lane handles j = q*128+2lane, +1)
    const int jA = q * 128 + 2 * lane, jB = jA + 1;
    const float wihA = W_ih[jA], wihB = W_ih[jB];
    const float bA = b_ih[jA] + b_hh[jA];
    const float bB = b_ih[jB] + b_hh[jB];

    // exchange pointers per parity
    unsigned long long* pollp[2];
    unsigned long long* pubp[2];
#pragma unroll
    for (int p = 0; p < 2; ++p) {
        pollp[p] = hg + (((size_t)p * BB + b) * 4 + w) * 64 + lane;
        pubp[p]  = hg + (((size_t)p * BB + b) * 4 + q) * 64 + lane;
    }

    __syncthreads();   // xrow visible

    // ================= main recurrence =================
#pragma unroll 1
    for (int t = 0; t < TT; ++t) {
        const int par = t & 1;
        float a0 = 0.f, a1 = 0.f;
        if (t > 0) {
            const unsigned* hsrc;
            if (w != q) {
                unsigned long long v = l2_read_u64(pollp[par]);
                while ((unsigned)(v >> 32) != (unsigned)t)
                    v = l2_read_u64(pollp[par]);
                h2w[w][lane] = (unsigned)v;      // wave-private region
                hsrc = &h2w[w][0];
            } else {
                hsrc = &h2local[par][0];         // own slice, written by this wave
            }
            const uint4* hp = reinterpret_cast<const uint4*>(hsrc);
#pragma unroll
            for (int c = 0; c < 16; ++c) {
                const uint4 u = hp[c];
                a0 = dot2f(u.x, wh0[4*c+0], a0); a1 = dot2f(u.x, wh1[4*c+0], a1);
                a0 = dot2f(u.y, wh0[4*c+1], a0); a1 = dot2f(u.y, wh1[4*c+1], a1);
                a0 = dot2f(u.z, wh0[4*c+2], a0); a1 = dot2f(u.z, wh1[4*c+2], a1);
                a0 = dot2f(u.w, wh0[4*c+3], a0); a1 = dot2f(u.w, wh1[4*c+3], a1);
            }
        }
        parts[par][w][lane]      = a0;
        parts[par][w][lane + 64] = a1;
        __syncthreads();   // the ONLY barrier per step

        if (w == q) {
            // reduce 4 k-partials for j = q*128 + 2*lane, +1; tanh; publish
            const int s2 = 2 * lane;
            const float* pb = &parts[par][0][0];
            const float2 p0 = *reinterpret_cast<const float2*>(pb + 0 * 128 + s2);
            const float2 p1 = *reinterpret_cast<const float2*>(pb + 1 * 128 + s2);
            const float2 p2 = *reinterpret_cast<const float2*>(pb + 2 * 128 + s2);
            const float2 p3 = *reinterpret_cast<const float2*>(pb + 3 * 128 + s2);
            float zA = (p0.x + p1.x) + (p2.x + p3.x);
            float zB = (p0.y + p1.y) + (p2.y + p3.y);
            const float xt = xrow[t];
            zA = fmaf(xt, wihA, zA + bA);
            zB = fmaf(xt, wihB, zB + bB);
            const float hA = fast_tanh(zA);
            const float hB = fast_tanh(zB);
            const unsigned du = pack_h2(hA, hB);
            const unsigned long long wv =
                ((unsigned long long)(unsigned)(t + 1) << 32) | du;
            l2_write_u64(pubp[par ^ 1], wv);     // publish FIRST (latency-critical)
            h2local[par ^ 1][lane] = du;         // own copy for next step
            if (t == TT - 1) {
                out[64 + b * HH + jA] = hA;
                out[64 + b * HH + jB] = hB;
            }
        }
        // waves w!=q fall through and immediately poll tag t+1 (overlaps publisher)
    }

    // ================= epilogue: out[b] = h_last . W_out + b_out =================
    if (q == 0 && w == 0) {
        float s = 0.f;
        {
            const __half2 hh = __builtin_bit_cast(__half2, h2local[TT & 1][lane]);
            s = fmaf(__low2float(hh),  W_out[2 * lane],     s);
            s = fmaf(__high2float(hh), W_out[2 * lane + 1], s);
        }
#pragma unroll
        for (int sl = 1; sl < 4; ++sl) {
            unsigned long long* p =
                hg + (((size_t)(TT & 1) * BB + b) * 4 + sl) * 64 + lane;
            unsigned long long v = l2_read_u64(p);
            while ((unsigned)(v >> 32) != (unsigned)TT) v = l2_read_u64(p);
            const __half2 hh = __builtin_bit_cast(__half2, (unsigned)v);
            s = fmaf(__low2float(hh),  W_out[sl * 128 + 2 * lane],     s);
            s = fmaf(__high2float(hh), W_out[sl * 128 + 2 * lane + 1], s);
        }
#pragma unroll
        for (int off = 32; off; off >>= 1) s += __shfl_down(s, off, 64);
        if (lane == 0) out[b] = s + b_out[0];
    }
}

extern "C" void kernel_launch(void* const* d_in, const int* in_sizes, int n_in,
                              void* d_out, int out_size, void* d_ws, size_t ws_size,
                              hipStream_t stream) {
    const float* x     = (const float*)d_in[0];  // inputs [B,T,1]
    // d_in[1] = state (ignored; reference uses zero initial hidden state)
    const float* W_ih  = (const float*)d_in[2];
    const float* W_hh  = (const float*)d_in[3];
    const float* b_ih  = (const float*)d_in[4];
    const float* b_hh  = (const float*)d_in[5];
    const float* W_out = (const float*)d_in[6];
    const float* b_out = (const float*)d_in[7];

    unsigned* ctl = (unsigned*)d_ws;                                   // 8KB bulletin
    unsigned long long* hg = (unsigned long long*)((char*)d_ws + 8192); // 256KB exchange

    // zero bulletin + exchange tags every call (ws is not re-poisoned between replays)
    hipMemsetAsync(d_ws, 0, 8192 + 2ull * BB * 4 * 64 * 8, stream);

    rnn_xcd<<<dim3(512), dim3(256), 0, stream>>>(
        x, W_ih, W_hh, b_ih, b_hh, W_out, b_out, (float*)d_out, ctl, hg);
}